// Round 1
// baseline (481.035 us; speedup 1.0000x reference)
//
#include <hip/hip_runtime.h>
#include <hip/hip_bf16.h>

#define H 128
#define KNB 48
#define NN 2048
#define BB 2
#define EPSF 1e-5f

typedef __bf16 bf16;
typedef bf16 bf16x8 __attribute__((ext_vector_type(8)));
typedef bf16 bf16x4 __attribute__((ext_vector_type(4)));
typedef float f32x4 __attribute__((ext_vector_type(4)));

__device__ __forceinline__ float gelu_f(float x) {
    return 0.5f * x * (1.0f + erff(x * 0.70710678118654752f));
}

// ---------------- weight prep: transpose + bf16 + fold duplicated h_E slice ----------------
// ws layout (bf16 elements):
//   Wm1T  [128][512] @ 0        (k segs: hV self | hE (W1b+W1d) | hV nbr | hVatom nbr)
//   W2T   [128][128] @ 65536
//   W3T   [128][128] @ 81920
//   W11T  [128][384] @ 98304
//   W12T  [128][128] @ 147456
//   W13T  [128][128] @ 163840
//   WinT  [512][128] @ 180224
//   WoutT [128][512] @ 245760   (total 311296)
__global__ void prep_weights(const float* __restrict__ W1, const float* __restrict__ W2,
                             const float* __restrict__ W3, const float* __restrict__ W11,
                             const float* __restrict__ W12, const float* __restrict__ W13,
                             const float* __restrict__ Win, const float* __restrict__ Wout,
                             bf16* __restrict__ ws)
{
    int i = blockIdx.x * 256 + threadIdx.x;
    float v;
    if (i < 65536) {
        int c = i >> 9, k = i & 511, s = k >> 7, k0 = k & 127;
        if (s == 0)      v = W1[k0 * H + c];
        else if (s == 1) v = W1[(128 + k0) * H + c] + W1[(384 + k0) * H + c];
        else if (s == 2) v = W1[(256 + k0) * H + c];
        else             v = W1[(512 + k0) * H + c];
    } else if (i < 81920)  { int j = i - 65536;  int c = j >> 7, k = j & 127; v = W2[k * H + c]; }
    else if (i < 98304)    { int j = i - 81920;  int c = j >> 7, k = j & 127; v = W3[k * H + c]; }
    else if (i < 147456)   { int j = i - 98304;  int c = j / 384, k = j - c * 384; v = W11[k * H + c]; }
    else if (i < 163840)   { int j = i - 147456; int c = j >> 7, k = j & 127; v = W12[k * H + c]; }
    else if (i < 180224)   { int j = i - 163840; int c = j >> 7, k = j & 127; v = W13[k * H + c]; }
    else if (i < 245760)   { int j = i - 180224; int jj = j >> 7, k = j & 127; v = Win[k * 512 + jj]; }
    else                   { int j = i - 245760; int c = j >> 9, k = j & 511; v = Wout[k * H + c]; }
    ws[i] = (bf16)v;
}

// ---------------- node kernel: message MLP + K-reduce + LN1 + FFN + LN2 ----------------
__global__ __launch_bounds__(256) void node_kernel(
    const float* __restrict__ hV, const float* __restrict__ hVa, const float* __restrict__ hE,
    const float* __restrict__ b1, const float* __restrict__ b2, const float* __restrict__ b3,
    const float* __restrict__ b_in, const float* __restrict__ b_out,
    const float* __restrict__ g1, const float* __restrict__ be1,
    const float* __restrict__ g2, const float* __restrict__ be2,
    const float* __restrict__ maskV, const float* __restrict__ maskA,
    const int* __restrict__ Eidx, const bf16* __restrict__ ws,
    float* __restrict__ outV)
{
    const bf16* Wm1T  = ws;
    const bf16* W2T   = ws + 65536;
    const bf16* W3T   = ws + 81920;
    const bf16* WinT  = ws + 180224;
    const bf16* WoutT = ws + 245760;

    int bn = blockIdx.x;
    int b  = bn >> 11;
    int t  = threadIdx.x, w = t >> 6, l = t & 63, l16 = l & 15, lg = l >> 4;

    __shared__ __align__(16) bf16 sA[48][136];
    __shared__ __align__(16) bf16 sH1[48][136];
    __shared__ __align__(16) bf16 sH2[48][136];
    __shared__ int   sIdx[48];
    __shared__ float sMask[48];
    __shared__ float sdh[128];
    __shared__ float sx[128];
    __shared__ float sHm[128];
    __shared__ float sFF[512];
    __shared__ float sred[2];

    if (t < 48) { sIdx[t] = Eidx[bn * 48 + t]; sMask[t] = maskA[bn * 48 + t]; }

    f32x4 acc[3][2];
    #pragma unroll
    for (int rt = 0; rt < 3; ++rt)
        #pragma unroll
        for (int c2 = 0; c2 < 2; ++c2) acc[rt][c2] = (f32x4){0.f, 0.f, 0.f, 0.f};

    // ---- GEMM1: 48x512 @ 512x128, streamed over 4 segments of 128 ----
    for (int seg = 0; seg < 4; ++seg) {
        if (seg == 0) __syncthreads();   // sIdx/sMask visible (and uniform barrier count)
        for (int e = t; e < 1536; e += 256) {
            int row = e >> 5, c4 = (e & 31) << 2;
            const float* src;
            if (seg == 0)      src = hV  + (size_t)bn * H + c4;
            else if (seg == 1) src = hE  + ((size_t)bn * 48 + row) * H + c4;
            else if (seg == 2) src = hV  + ((size_t)(b * NN + sIdx[row])) * H + c4;
            else               src = hVa + ((size_t)(b * NN + sIdx[row])) * H + c4;
            float4 v = *reinterpret_cast<const float4*>(src);
            bf16x4 o; o[0] = (bf16)v.x; o[1] = (bf16)v.y; o[2] = (bf16)v.z; o[3] = (bf16)v.w;
            *reinterpret_cast<bf16x4*>(&sA[row][c4]) = o;
        }
        __syncthreads();
        #pragma unroll
        for (int kk = 0; kk < 4; ++kk) {
            bf16x8 af[3];
            #pragma unroll
            for (int rt = 0; rt < 3; ++rt)
                af[rt] = *reinterpret_cast<const bf16x8*>(&sA[rt * 16 + l16][kk * 32 + lg * 8]);
            #pragma unroll
            for (int c2 = 0; c2 < 2; ++c2) {
                int c = (w * 2 + c2) * 16 + l16;
                bf16x8 bf_ = *reinterpret_cast<const bf16x8*>(&Wm1T[c * 512 + seg * 128 + kk * 32 + lg * 8]);
                #pragma unroll
                for (int rt = 0; rt < 3; ++rt)
                    acc[rt][c2] = __builtin_amdgcn_mfma_f32_16x16x32_bf16(af[rt], bf_, acc[rt][c2], 0, 0, 0);
            }
        }
        __syncthreads();
    }
    // epilogue: gelu(x + b1) -> sH1
    #pragma unroll
    for (int rt = 0; rt < 3; ++rt)
        #pragma unroll
        for (int c2 = 0; c2 < 2; ++c2) {
            int col = (w * 2 + c2) * 16 + l16;
            float bb = b1[col];
            #pragma unroll
            for (int i = 0; i < 4; ++i) {
                int row = rt * 16 + lg * 4 + i;
                sH1[row][col] = (bf16)gelu_f(acc[rt][c2][i] + bb);
            }
        }
    __syncthreads();

    // ---- GEMM2: 48x128 @ 128x128, gelu -> sH2 ----
    f32x4 acc2[3][2];
    #pragma unroll
    for (int rt = 0; rt < 3; ++rt)
        #pragma unroll
        for (int c2 = 0; c2 < 2; ++c2) acc2[rt][c2] = (f32x4){0.f, 0.f, 0.f, 0.f};
    #pragma unroll
    for (int kk = 0; kk < 4; ++kk) {
        bf16x8 af[3];
        #pragma unroll
        for (int rt = 0; rt < 3; ++rt)
            af[rt] = *reinterpret_cast<const bf16x8*>(&sH1[rt * 16 + l16][kk * 32 + lg * 8]);
        #pragma unroll
        for (int c2 = 0; c2 < 2; ++c2) {
            int c = (w * 2 + c2) * 16 + l16;
            bf16x8 bf_ = *reinterpret_cast<const bf16x8*>(&W2T[c * 128 + kk * 32 + lg * 8]);
            #pragma unroll
            for (int rt = 0; rt < 3; ++rt)
                acc2[rt][c2] = __builtin_amdgcn_mfma_f32_16x16x32_bf16(af[rt], bf_, acc2[rt][c2], 0, 0, 0);
        }
    }
    #pragma unroll
    for (int rt = 0; rt < 3; ++rt)
        #pragma unroll
        for (int c2 = 0; c2 < 2; ++c2) {
            int col = (w * 2 + c2) * 16 + l16;
            float bb = b2[col];
            #pragma unroll
            for (int i = 0; i < 4; ++i) {
                int row = rt * 16 + lg * 4 + i;
                sH2[row][col] = (bf16)gelu_f(acc2[rt][c2][i] + bb);
            }
        }
    __syncthreads();

    // ---- GEMM3: 48x128 @ 128x128, + b3, mask, reduce over 48 rows ----
    f32x4 acc3[3][2];
    #pragma unroll
    for (int rt = 0; rt < 3; ++rt)
        #pragma unroll
        for (int c2 = 0; c2 < 2; ++c2) acc3[rt][c2] = (f32x4){0.f, 0.f, 0.f, 0.f};
    #pragma unroll
    for (int kk = 0; kk < 4; ++kk) {
        bf16x8 af[3];
        #pragma unroll
        for (int rt = 0; rt < 3; ++rt)
            af[rt] = *reinterpret_cast<const bf16x8*>(&sH2[rt * 16 + l16][kk * 32 + lg * 8]);
        #pragma unroll
        for (int c2 = 0; c2 < 2; ++c2) {
            int c = (w * 2 + c2) * 16 + l16;
            bf16x8 bf_ = *reinterpret_cast<const bf16x8*>(&W3T[c * 128 + kk * 32 + lg * 8]);
            #pragma unroll
            for (int rt = 0; rt < 3; ++rt)
                acc3[rt][c2] = __builtin_amdgcn_mfma_f32_16x16x32_bf16(af[rt], bf_, acc3[rt][c2], 0, 0, 0);
        }
    }
    float red[2];
    #pragma unroll
    for (int c2 = 0; c2 < 2; ++c2) {
        int col = (w * 2 + c2) * 16 + l16;
        float bb = b3[col];
        float s = 0.f;
        #pragma unroll
        for (int rt = 0; rt < 3; ++rt)
            #pragma unroll
            for (int i = 0; i < 4; ++i) {
                int row = rt * 16 + lg * 4 + i;
                s += (acc3[rt][c2][i] + bb) * sMask[row];
            }
        s += __shfl_xor(s, 16);
        s += __shfl_xor(s, 32);
        red[c2] = s;
    }
    if (l < 16) { sdh[w * 32 + l] = red[0]; sdh[w * 32 + 16 + l] = red[1]; }
    __syncthreads();

    // ---- LN1 ----
    if (t < 128) sx[t] = hV[(size_t)bn * H + t] + sdh[t] * (1.0f / 30.0f);
    __syncthreads();
    if (w == 0) {
        float xa = sx[l], xb = sx[l + 64];
        float s1 = xa + xb, s2 = xa * xa + xb * xb;
        #pragma unroll
        for (int off = 32; off; off >>= 1) { s1 += __shfl_xor(s1, off); s2 += __shfl_xor(s2, off); }
        if (l == 0) { float m = s1 * (1.f / 128.f); sred[0] = m; sred[1] = s2 * (1.f / 128.f) - m * m; }
    }
    __syncthreads();
    if (t < 128) {
        float xn = (sx[t] - sred[0]) * rsqrtf(sred[1] + EPSF);
        sHm[t] = xn * g1[t] + be1[t];
    }
    __syncthreads();

    // ---- FFN: 128 -> 512 (gelu) -> 128 ----
    #pragma unroll
    for (int rep = 0; rep < 2; ++rep) {
        int j = t + rep * 256;
        float a = b_in[j];
        for (int k = 0; k < 128; k += 8) {
            bf16x8 wv = *reinterpret_cast<const bf16x8*>(&WinT[j * 128 + k]);
            #pragma unroll
            for (int q = 0; q < 8; ++q) a += sHm[k + q] * (float)wv[q];
        }
        sFF[j] = gelu_f(a);
    }
    __syncthreads();
    if (t < 128) {
        float a = b_out[t];
        for (int k = 0; k < 512; k += 8) {
            bf16x8 wv = *reinterpret_cast<const bf16x8*>(&WoutT[t * 512 + k]);
            #pragma unroll
            for (int q = 0; q < 8; ++q) a += sFF[k + q] * (float)wv[q];
        }
        sx[t] = sHm[t] + a;
    }
    __syncthreads();

    // ---- LN2 + mask_V + store ----
    if (w == 0) {
        float xa = sx[l], xb = sx[l + 64];
        float s1 = xa + xb, s2 = xa * xa + xb * xb;
        #pragma unroll
        for (int off = 32; off; off >>= 1) { s1 += __shfl_xor(s1, off); s2 += __shfl_xor(s2, off); }
        if (l == 0) { float m = s1 * (1.f / 128.f); sred[0] = m; sred[1] = s2 * (1.f / 128.f) - m * m; }
    }
    __syncthreads();
    if (t < 128) {
        float xn = (sx[t] - sred[0]) * rsqrtf(sred[1] + EPSF);
        float y = (xn * g2[t] + be2[t]) * maskV[bn];
        outV[(size_t)bn * H + t] = y;
    }
}

// ---------------- edge kernel: edge MLP + residual LN over rows ----------------
__global__ __launch_bounds__(256) void edge_kernel(
    const float* __restrict__ hE,
    const float* __restrict__ b11, const float* __restrict__ b12, const float* __restrict__ b13,
    const float* __restrict__ g3, const float* __restrict__ be3,
    const int* __restrict__ Eidx, const bf16* __restrict__ ws,
    const float* __restrict__ hV2, float* __restrict__ outE)
{
    const bf16* W11T = ws + 98304;   // [128][384]
    const bf16* W12T = ws + 147456;  // [128][128]
    const bf16* W13T = ws + 163840;  // [128][128]

    int bn = blockIdx.x, b = bn >> 11;
    int t = threadIdx.x, w = t >> 6, l = t & 63, l16 = l & 15, lg = l >> 4;

    __shared__ __align__(16) char sbuf[39168];     // sA | sH1 | sH2 ; sM2 overlays sA+sH1
    bf16 (*sA)[136]  = reinterpret_cast<bf16(*)[136]>(sbuf);
    bf16 (*sH1)[136] = reinterpret_cast<bf16(*)[136]>(sbuf + 13056);
    bf16 (*sH2)[136] = reinterpret_cast<bf16(*)[136]>(sbuf + 26112);
    float (*sM2)[132] = reinterpret_cast<float(*)[132]>(sbuf);   // 25344 B <= 26112 B
    __shared__ __align__(16) float sHE[48][132];
    __shared__ int sIdx[48];

    if (t < 48) sIdx[t] = Eidx[bn * 48 + t];

    f32x4 acc[3][2];
    #pragma unroll
    for (int rt = 0; rt < 3; ++rt)
        #pragma unroll
        for (int c2 = 0; c2 < 2; ++c2) acc[rt][c2] = (f32x4){0.f, 0.f, 0.f, 0.f};

    // ---- GEMM1: 48x384 @ 384x128 streamed over 3 segments ----
    for (int seg = 0; seg < 3; ++seg) {
        if (seg == 0) __syncthreads();   // sIdx visible
        for (int e = t; e < 1536; e += 256) {
            int row = e >> 5, c4 = (e & 31) << 2;
            const float* src;
            if (seg == 0)      src = hV2 + (size_t)bn * H + c4;
            else if (seg == 1) src = hE  + ((size_t)bn * 48 + row) * H + c4;
            else               src = hV2 + ((size_t)(b * NN + sIdx[row])) * H + c4;
            float4 v = *reinterpret_cast<const float4*>(src);
            if (seg == 1) *reinterpret_cast<float4*>(&sHE[row][c4]) = v;
            bf16x4 o; o[0] = (bf16)v.x; o[1] = (bf16)v.y; o[2] = (bf16)v.z; o[3] = (bf16)v.w;
            *reinterpret_cast<bf16x4*>(&sA[row][c4]) = o;
        }
        __syncthreads();
        #pragma unroll
        for (int kk = 0; kk < 4; ++kk) {
            bf16x8 af[3];
            #pragma unroll
            for (int rt = 0; rt < 3; ++rt)
                af[rt] = *reinterpret_cast<const bf16x8*>(&sA[rt * 16 + l16][kk * 32 + lg * 8]);
            #pragma unroll
            for (int c2 = 0; c2 < 2; ++c2) {
                int c = (w * 2 + c2) * 16 + l16;
                bf16x8 bf_ = *reinterpret_cast<const bf16x8*>(&W11T[c * 384 + seg * 128 + kk * 32 + lg * 8]);
                #pragma unroll
                for (int rt = 0; rt < 3; ++rt)
                    acc[rt][c2] = __builtin_amdgcn_mfma_f32_16x16x32_bf16(af[rt], bf_, acc[rt][c2], 0, 0, 0);
            }
        }
        __syncthreads();
    }
    #pragma unroll
    for (int rt = 0; rt < 3; ++rt)
        #pragma unroll
        for (int c2 = 0; c2 < 2; ++c2) {
            int col = (w * 2 + c2) * 16 + l16;
            float bb = b11[col];
            #pragma unroll
            for (int i = 0; i < 4; ++i) {
                int row = rt * 16 + lg * 4 + i;
                sH1[row][col] = (bf16)gelu_f(acc[rt][c2][i] + bb);
            }
        }
    __syncthreads();

    // ---- GEMM2 ----
    f32x4 acc2[3][2];
    #pragma unroll
    for (int rt = 0; rt < 3; ++rt)
        #pragma unroll
        for (int c2 = 0; c2 < 2; ++c2) acc2[rt][c2] = (f32x4){0.f, 0.f, 0.f, 0.f};
    #pragma unroll
    for (int kk = 0; kk < 4; ++kk) {
        bf16x8 af[3];
        #pragma unroll
        for (int rt = 0; rt < 3; ++rt)
            af[rt] = *reinterpret_cast<const bf16x8*>(&sH1[rt * 16 + l16][kk * 32 + lg * 8]);
        #pragma unroll
        for (int c2 = 0; c2 < 2; ++c2) {
            int c = (w * 2 + c2) * 16 + l16;
            bf16x8 bf_ = *reinterpret_cast<const bf16x8*>(&W12T[c * 128 + kk * 32 + lg * 8]);
            #pragma unroll
            for (int rt = 0; rt < 3; ++rt)
                acc2[rt][c2] = __builtin_amdgcn_mfma_f32_16x16x32_bf16(af[rt], bf_, acc2[rt][c2], 0, 0, 0);
        }
    }
    #pragma unroll
    for (int rt = 0; rt < 3; ++rt)
        #pragma unroll
        for (int c2 = 0; c2 < 2; ++c2) {
            int col = (w * 2 + c2) * 16 + l16;
            float bb = b12[col];
            #pragma unroll
            for (int i = 0; i < 4; ++i) {
                int row = rt * 16 + lg * 4 + i;
                sH2[row][col] = (bf16)gelu_f(acc2[rt][c2][i] + bb);
            }
        }
    __syncthreads();   // sH2 ready; also: all sH1 reads done -> sM2 overlay safe after this

    // ---- GEMM3 ----
    f32x4 acc3[3][2];
    #pragma unroll
    for (int rt = 0; rt < 3; ++rt)
        #pragma unroll
        for (int c2 = 0; c2 < 2; ++c2) acc3[rt][c2] = (f32x4){0.f, 0.f, 0.f, 0.f};
    #pragma unroll
    for (int kk = 0; kk < 4; ++kk) {
        bf16x8 af[3];
        #pragma unroll
        for (int rt = 0; rt < 3; ++rt)
            af[rt] = *reinterpret_cast<const bf16x8*>(&sH2[rt * 16 + l16][kk * 32 + lg * 8]);
        #pragma unroll
        for (int c2 = 0; c2 < 2; ++c2) {
            int c = (w * 2 + c2) * 16 + l16;
            bf16x8 bf_ = *reinterpret_cast<const bf16x8*>(&W13T[c * 128 + kk * 32 + lg * 8]);
            #pragma unroll
            for (int rt = 0; rt < 3; ++rt)
                acc3[rt][c2] = __builtin_amdgcn_mfma_f32_16x16x32_bf16(af[rt], bf_, acc3[rt][c2], 0, 0, 0);
        }
    }
    #pragma unroll
    for (int rt = 0; rt < 3; ++rt)
        #pragma unroll
        for (int c2 = 0; c2 < 2; ++c2) {
            int col = (w * 2 + c2) * 16 + l16;
            float bb = b13[col];
            #pragma unroll
            for (int i = 0; i < 4; ++i) {
                int row = rt * 16 + lg * 4 + i;
                sM2[row][col] = acc3[rt][c2][i] + bb;
            }
        }
    __syncthreads();

    // ---- per-row LayerNorm(h_E + m2) ----
    if (t < 192) {
        int row = t >> 2, q = t & 3;
        float xr[32];
        float s1 = 0.f, s2 = 0.f;
        #pragma unroll
        for (int j = 0; j < 32; ++j) {
            float x = sHE[row][q * 32 + j] + sM2[row][q * 32 + j];
            xr[j] = x; s1 += x; s2 += x * x;
        }
        s1 += __shfl_xor(s1, 1); s1 += __shfl_xor(s1, 2);
        s2 += __shfl_xor(s2, 1); s2 += __shfl_xor(s2, 2);
        float m = s1 * (1.f / 128.f);
        float vv = s2 * (1.f / 128.f) - m * m;
        float rs = rsqrtf(vv + EPSF);
        float* dst = outE + ((size_t)bn * 48 + row) * H + q * 32;
        #pragma unroll
        for (int j = 0; j < 32; ++j) {
            int c = q * 32 + j;
            dst[j] = (xr[j] - m) * rs * g3[c] + be3[c];
        }
    }
}

extern "C" void kernel_launch(void* const* d_in, const int* in_sizes, int n_in,
                              void* d_out, int out_size, void* d_ws, size_t ws_size,
                              hipStream_t stream)
{
    const float* hV    = (const float*)d_in[0];
    const float* hVa   = (const float*)d_in[1];
    const float* hE    = (const float*)d_in[2];
    const float* W1    = (const float*)d_in[3];
    const float* b1    = (const float*)d_in[4];
    const float* W2    = (const float*)d_in[5];
    const float* b2    = (const float*)d_in[6];
    const float* W3    = (const float*)d_in[7];
    const float* b3    = (const float*)d_in[8];
    const float* W11   = (const float*)d_in[9];
    const float* b11   = (const float*)d_in[10];
    const float* W12   = (const float*)d_in[11];
    const float* b12   = (const float*)d_in[12];
    const float* W13   = (const float*)d_in[13];
    const float* b13   = (const float*)d_in[14];
    const float* Win   = (const float*)d_in[15];
    const float* b_in  = (const float*)d_in[16];
    const float* Wout  = (const float*)d_in[17];
    const float* b_out = (const float*)d_in[18];
    const float* g1    = (const float*)d_in[19];
    const float* be1   = (const float*)d_in[20];
    const float* g2    = (const float*)d_in[21];
    const float* be2   = (const float*)d_in[22];
    const float* g3    = (const float*)d_in[23];
    const float* be3   = (const float*)d_in[24];
    const float* maskV = (const float*)d_in[25];
    const float* maskA = (const float*)d_in[26];
    const int*   Eidx  = (const int*)  d_in[27];

    bf16*  ws   = (bf16*)d_ws;
    float* outV = (float*)d_out;
    float* outE = outV + (size_t)BB * NN * H;

    prep_weights<<<1216, 256, 0, stream>>>(W1, W2, W3, W11, W12, W13, Win, Wout, ws);
    node_kernel<<<BB * NN, 256, 0, stream>>>(hV, hVa, hE, b1, b2, b3, b_in, b_out,
                                             g1, be1, g2, be2, maskV, maskA, Eidx, ws, outV);
    edge_kernel<<<BB * NN, 256, 0, stream>>>(hE, b11, b12, b13, g3, be3, Eidx, ws, outV, outE);
}

// Round 2
// 281.247 us; speedup vs baseline: 1.7104x; 1.7104x over previous
//
#include <hip/hip_runtime.h>
#include <hip/hip_bf16.h>

#define H 128
#define NN 2048
#define BB 2
#define EPSF 1e-5f

typedef __bf16 bf16;
typedef bf16 bf16x8 __attribute__((ext_vector_type(8)));
typedef bf16 bf16x4 __attribute__((ext_vector_type(4)));
typedef float f32x4 __attribute__((ext_vector_type(4)));

// ---- ws layout ----
// bf16 elems [0, 311296): weights (same as round 1 prep layout)
//   Wm1T full [128][512] @ 0      (k segs: self | hE-fold | hV_nb | hVa_nb)
//   W2T   @ 65536, W3T @ 81920
//   W11T full [128][384] @ 98304  (k segs: self | hE | hV2_nb)
//   W12T  @ 147456, W13T @ 163840
//   WinT [512][128] @ 180224, WoutT [128][512] @ 245760
// f32 elems (on (float*)ws):
#define U1_F     155648
#define U2_F     679936
#define HVMID_F  1204224
// bf16 elems:
#define HVMID_B  3457024
#define HV2_B    3981312
#define HV_B     4505600
#define HVA_B    5029888
// total = 5554176 bf16 elems = 11,108,352 bytes of ws

__device__ __forceinline__ float gelu_f(float x) {
    return 0.5f * x * (1.0f + erff(x * 0.70710678118654752f));
}

// ---------------- weight prep (unchanged from round 1) ----------------
__global__ void prep_weights(const float* __restrict__ W1, const float* __restrict__ W2,
                             const float* __restrict__ W3, const float* __restrict__ W11,
                             const float* __restrict__ W12, const float* __restrict__ W13,
                             const float* __restrict__ Win, const float* __restrict__ Wout,
                             bf16* __restrict__ ws)
{
    int i = blockIdx.x * 256 + threadIdx.x;
    float v;
    if (i < 65536) {
        int c = i >> 9, k = i & 511, s = k >> 7, k0 = k & 127;
        if (s == 0)      v = W1[k0 * H + c];
        else if (s == 1) v = W1[(128 + k0) * H + c] + W1[(384 + k0) * H + c];
        else if (s == 2) v = W1[(256 + k0) * H + c];
        else             v = W1[(512 + k0) * H + c];
    } else if (i < 81920)  { int j = i - 65536;  int c = j >> 7, k = j & 127; v = W2[k * H + c]; }
    else if (i < 98304)    { int j = i - 81920;  int c = j >> 7, k = j & 127; v = W3[k * H + c]; }
    else if (i < 147456)   { int j = i - 98304;  int c = j / 384, k = j - c * 384; v = W11[k * H + c]; }
    else if (i < 163840)   { int j = i - 147456; int c = j >> 7, k = j & 127; v = W12[k * H + c]; }
    else if (i < 180224)   { int j = i - 163840; int c = j >> 7, k = j & 127; v = W13[k * H + c]; }
    else if (i < 245760)   { int j = i - 180224; int jj = j >> 7, k = j & 127; v = Win[k * 512 + jj]; }
    else                   { int j = i - 245760; int c = j >> 9, k = j & 511; v = Wout[k * H + c]; }
    ws[i] = (bf16)v;
}

// ---------------- U1 = hV @ W1a + b1 ; also emit bf16 copies of hV, hVa ----------------
__global__ __launch_bounds__(512) void u1_kernel(
    const float* __restrict__ hV, const float* __restrict__ hVa,
    const float* __restrict__ b1, bf16* __restrict__ ws, float* __restrict__ wsf)
{
    int n0 = blockIdx.x * 128;
    int t = threadIdx.x, w = t >> 6, l = t & 63, l16 = l & 15, lg = l >> 4;
    int wm = w >> 2, wn = w & 3;
    __shared__ __align__(16) bf16 sA[128][136];

    #pragma unroll
    for (int i = 0; i < 8; ++i) {
        int idx = t + i * 512;
        int row = idx >> 5, c4 = (idx & 31) << 2;
        f32x4 v = *(const f32x4*)(hV + (size_t)(n0 + row) * H + c4);
        bf16x4 o; o[0] = (bf16)v[0]; o[1] = (bf16)v[1]; o[2] = (bf16)v[2]; o[3] = (bf16)v[3];
        *(bf16x4*)(&sA[row][c4]) = o;
        *(bf16x4*)(ws + HV_B + (size_t)(n0 + row) * H + c4) = o;
        f32x4 va = *(const f32x4*)(hVa + (size_t)(n0 + row) * H + c4);
        bf16x4 oa; oa[0] = (bf16)va[0]; oa[1] = (bf16)va[1]; oa[2] = (bf16)va[2]; oa[3] = (bf16)va[3];
        *(bf16x4*)(ws + HVA_B + (size_t)(n0 + row) * H + c4) = oa;
    }
    __syncthreads();

    f32x4 acc[4][2];
    #pragma unroll
    for (int rt = 0; rt < 4; ++rt)
        #pragma unroll
        for (int c2 = 0; c2 < 2; ++c2) acc[rt][c2] = (f32x4){0.f, 0.f, 0.f, 0.f};
    #pragma unroll
    for (int kk = 0; kk < 4; ++kk) {
        bf16x8 af[4];
        #pragma unroll
        for (int rt = 0; rt < 4; ++rt)
            af[rt] = *(const bf16x8*)(&sA[wm * 64 + rt * 16 + l16][kk * 32 + lg * 8]);
        #pragma unroll
        for (int c2 = 0; c2 < 2; ++c2) {
            int c = wn * 32 + c2 * 16 + l16;
            bf16x8 bfr = *(const bf16x8*)(&ws[(size_t)c * 512 + kk * 32 + lg * 8]);
            #pragma unroll
            for (int rt = 0; rt < 4; ++rt)
                acc[rt][c2] = __builtin_amdgcn_mfma_f32_16x16x32_bf16(af[rt], bfr, acc[rt][c2], 0, 0, 0);
        }
    }
    #pragma unroll
    for (int c2 = 0; c2 < 2; ++c2) {
        int col = wn * 32 + c2 * 16 + l16;
        float bb = b1[col];
        #pragma unroll
        for (int rt = 0; rt < 4; ++rt)
            #pragma unroll
            for (int i = 0; i < 4; ++i) {
                int row = wm * 64 + rt * 16 + lg * 4 + i;
                wsf[U1_F + (size_t)(n0 + row) * H + col] = acc[rt][c2][i] + bb;
            }
    }
}

// ---------------- node message: 2 nodes/block, M=96, segs {hE, hV_nb, hVa_nb} ----------------
__global__ __launch_bounds__(512, 4) void node_msg_kernel(
    const float* __restrict__ hV, const float* __restrict__ hE,
    const float* __restrict__ b2, const float* __restrict__ b3,
    const float* __restrict__ g1, const float* __restrict__ be1,
    const float* __restrict__ maskA, const int* __restrict__ Eidx,
    bf16* __restrict__ ws, float* __restrict__ wsf)
{
    int bn0 = blockIdx.x * 2;
    int b = bn0 >> 11;
    int t = threadIdx.x, w = t >> 6, l = t & 63, l16 = l & 15, lg = l >> 4;
    int wm = w >> 2, wn = w & 3;

    __shared__ __align__(16) char smem[55056];
    bf16 (*sA)[136]  = (bf16(*)[136])(smem);           // P: sA, later sH2
    bf16 (*sH2)[136] = (bf16(*)[136])(smem);
    bf16 (*sH1)[136] = (bf16(*)[136])(smem + 26112);   // Q
    float* sdh  = (float*)(smem + 52224);
    float* sx   = (float*)(smem + 53248);
    float* sred = (float*)(smem + 54272);
    int*   sIdx = (int*)(smem + 54288);
    float* sMsk = (float*)(smem + 54672);

    if (t < 96) { sIdx[t] = Eidx[bn0 * 48 + t]; sMsk[t] = maskA[bn0 * 48 + t]; }

    f32x4 acc[3][2];
    #pragma unroll
    for (int rt = 0; rt < 3; ++rt)
        #pragma unroll
        for (int c2 = 0; c2 < 2; ++c2) acc[rt][c2] = (f32x4){0.f, 0.f, 0.f, 0.f};

    for (int seg = 0; seg < 3; ++seg) {
        if (seg == 0) __syncthreads();   // sIdx ready
        if (seg == 0) {
            #pragma unroll
            for (int i = 0; i < 6; ++i) {
                int idx = t + i * 512;
                int row = idx >> 5, c4 = (idx & 31) << 2;
                f32x4 v = *(const f32x4*)(hE + ((size_t)bn0 * 48 + row) * H + c4);
                bf16x4 o; o[0] = (bf16)v[0]; o[1] = (bf16)v[1]; o[2] = (bf16)v[2]; o[3] = (bf16)v[3];
                *(bf16x4*)(&sA[row][c4]) = o;
            }
        } else {
            const bf16* src = ws + (seg == 1 ? HV_B : HVA_B) + (size_t)b * NN * H;
            #pragma unroll
            for (int i = 0; i < 3; ++i) {
                int idx = t + i * 512;
                int row = idx >> 4, c8 = (idx & 15) << 3;
                bf16x8 v = *(const bf16x8*)(src + (size_t)sIdx[row] * H + c8);
                *(bf16x8*)(&sA[row][c8]) = v;
            }
        }
        __syncthreads();
        #pragma unroll
        for (int kk = 0; kk < 4; ++kk) {
            bf16x8 af[3];
            #pragma unroll
            for (int rt = 0; rt < 3; ++rt)
                af[rt] = *(const bf16x8*)(&sA[wm * 48 + rt * 16 + l16][kk * 32 + lg * 8]);
            #pragma unroll
            for (int c2 = 0; c2 < 2; ++c2) {
                int c = wn * 32 + c2 * 16 + l16;
                bf16x8 bfr = *(const bf16x8*)(&ws[(size_t)c * 512 + 128 + seg * 128 + kk * 32 + lg * 8]);
                #pragma unroll
                for (int rt = 0; rt < 3; ++rt)
                    acc[rt][c2] = __builtin_amdgcn_mfma_f32_16x16x32_bf16(af[rt], bfr, acc[rt][c2], 0, 0, 0);
            }
        }
        __syncthreads();
    }
    // epi1: + U1 (has b1), gelu -> sH1
    #pragma unroll
    for (int c2 = 0; c2 < 2; ++c2) {
        int col = wn * 32 + c2 * 16 + l16;
        float u = wsf[U1_F + (size_t)(bn0 + wm) * H + col];
        #pragma unroll
        for (int rt = 0; rt < 3; ++rt)
            #pragma unroll
            for (int i = 0; i < 4; ++i) {
                int row = wm * 48 + rt * 16 + lg * 4 + i;
                sH1[row][col] = (bf16)gelu_f(acc[rt][c2][i] + u);
            }
    }
    __syncthreads();

    // GEMM2
    f32x4 a2[3][2];
    #pragma unroll
    for (int rt = 0; rt < 3; ++rt)
        #pragma unroll
        for (int c2 = 0; c2 < 2; ++c2) a2[rt][c2] = (f32x4){0.f, 0.f, 0.f, 0.f};
    #pragma unroll
    for (int kk = 0; kk < 4; ++kk) {
        bf16x8 af[3];
        #pragma unroll
        for (int rt = 0; rt < 3; ++rt)
            af[rt] = *(const bf16x8*)(&sH1[wm * 48 + rt * 16 + l16][kk * 32 + lg * 8]);
        #pragma unroll
        for (int c2 = 0; c2 < 2; ++c2) {
            int c = wn * 32 + c2 * 16 + l16;
            bf16x8 bfr = *(const bf16x8*)(&ws[65536 + (size_t)c * 128 + kk * 32 + lg * 8]);
            #pragma unroll
            for (int rt = 0; rt < 3; ++rt)
                a2[rt][c2] = __builtin_amdgcn_mfma_f32_16x16x32_bf16(af[rt], bfr, a2[rt][c2], 0, 0, 0);
        }
    }
    #pragma unroll
    for (int c2 = 0; c2 < 2; ++c2) {
        int col = wn * 32 + c2 * 16 + l16;
        float bb = b2[col];
        #pragma unroll
        for (int rt = 0; rt < 3; ++rt)
            #pragma unroll
            for (int i = 0; i < 4; ++i) {
                int row = wm * 48 + rt * 16 + lg * 4 + i;
                sH2[row][col] = (bf16)gelu_f(a2[rt][c2][i] + bb);
            }
    }
    __syncthreads();

    // GEMM3 + masked reduce over 48 edges (per node)
    f32x4 a3[3][2];
    #pragma unroll
    for (int rt = 0; rt < 3; ++rt)
        #pragma unroll
        for (int c2 = 0; c2 < 2; ++c2) a3[rt][c2] = (f32x4){0.f, 0.f, 0.f, 0.f};
    #pragma unroll
    for (int kk = 0; kk < 4; ++kk) {
        bf16x8 af[3];
        #pragma unroll
        for (int rt = 0; rt < 3; ++rt)
            af[rt] = *(const bf16x8*)(&sH2[wm * 48 + rt * 16 + l16][kk * 32 + lg * 8]);
        #pragma unroll
        for (int c2 = 0; c2 < 2; ++c2) {
            int c = wn * 32 + c2 * 16 + l16;
            bf16x8 bfr = *(const bf16x8*)(&ws[81920 + (size_t)c * 128 + kk * 32 + lg * 8]);
            #pragma unroll
            for (int rt = 0; rt < 3; ++rt)
                a3[rt][c2] = __builtin_amdgcn_mfma_f32_16x16x32_bf16(af[rt], bfr, a3[rt][c2], 0, 0, 0);
        }
    }
    #pragma unroll
    for (int c2 = 0; c2 < 2; ++c2) {
        int col = wn * 32 + c2 * 16 + l16;
        float bb = b3[col];
        float s = 0.f;
        #pragma unroll
        for (int rt = 0; rt < 3; ++rt)
            #pragma unroll
            for (int i = 0; i < 4; ++i) {
                int ri = rt * 16 + lg * 4 + i;
                s += (a3[rt][c2][i] + bb) * sMsk[wm * 48 + ri];
            }
        s += __shfl_xor(s, 16);
        s += __shfl_xor(s, 32);
        if (l < 16) sdh[wm * 128 + wn * 32 + c2 * 16 + l16] = s;
    }
    __syncthreads();

    // LN1 over 2 nodes
    if (t < 256) {
        int nl = t >> 7, col = t & 127;
        sx[t] = hV[(size_t)(bn0 + nl) * H + col] + sdh[t] * (1.0f / 30.0f);
    }
    __syncthreads();
    if (w < 2) {
        float xa = sx[w * 128 + l], xb = sx[w * 128 + l + 64];
        float s1 = xa + xb, s2 = xa * xa + xb * xb;
        #pragma unroll
        for (int off = 32; off; off >>= 1) { s1 += __shfl_xor(s1, off); s2 += __shfl_xor(s2, off); }
        if (l == 0) { float m = s1 * (1.f / 128.f); sred[w * 2] = m; sred[w * 2 + 1] = s2 * (1.f / 128.f) - m * m; }
    }
    __syncthreads();
    if (t < 256) {
        int nl = t >> 7, col = t & 127;
        float y = (sx[t] - sred[nl * 2]) * rsqrtf(sred[nl * 2 + 1] + EPSF) * g1[col] + be1[col];
        wsf[HVMID_F + (size_t)(bn0 + nl) * H + col] = y;
        ws[HVMID_B + (size_t)(bn0 + nl) * H + col] = (bf16)y;
    }
}

// ---------------- FFN batched: 32 nodes/block, + LN2 + maskV + U2 ----------------
__global__ __launch_bounds__(512) void ffn_kernel(
    const float* __restrict__ b_in, const float* __restrict__ b_out,
    const float* __restrict__ b11, const float* __restrict__ g2,
    const float* __restrict__ be2, const float* __restrict__ maskV,
    bf16* __restrict__ ws, float* __restrict__ wsf, float* __restrict__ outV)
{
    int n0 = blockIdx.x * 32;
    int t = threadIdx.x, w = t >> 6, l = t & 63, l16 = l & 15, lg = l >> 4;

    __shared__ __align__(16) char smem[8704 + 33280];
    bf16 (*sA)[136]  = (bf16(*)[136])(smem);
    bf16 (*sFF)[520] = (bf16(*)[520])(smem + 8704);
    float (*sX)[132] = (float(*)[132])(smem + 8704);   // overlays sFF

    {
        int row = t >> 4, c8 = (t & 15) << 3;
        *(bf16x8*)(&sA[row][c8]) = *(const bf16x8*)(ws + HVMID_B + (size_t)(n0 + row) * H + c8);
    }
    __syncthreads();

    // GEMM1: 32x128 @ 128x512
    f32x4 a1[2][4];
    #pragma unroll
    for (int rt = 0; rt < 2; ++rt)
        #pragma unroll
        for (int ct = 0; ct < 4; ++ct) a1[rt][ct] = (f32x4){0.f, 0.f, 0.f, 0.f};
    #pragma unroll
    for (int kk = 0; kk < 4; ++kk) {
        bf16x8 af[2];
        #pragma unroll
        for (int rt = 0; rt < 2; ++rt)
            af[rt] = *(const bf16x8*)(&sA[rt * 16 + l16][kk * 32 + lg * 8]);
        #pragma unroll
        for (int ct = 0; ct < 4; ++ct) {
            int c = w * 64 + ct * 16 + l16;
            bf16x8 bfr = *(const bf16x8*)(&ws[180224 + (size_t)c * 128 + kk * 32 + lg * 8]);
            #pragma unroll
            for (int rt = 0; rt < 2; ++rt)
                a1[rt][ct] = __builtin_amdgcn_mfma_f32_16x16x32_bf16(af[rt], bfr, a1[rt][ct], 0, 0, 0);
        }
    }
    #pragma unroll
    for (int ct = 0; ct < 4; ++ct) {
        int c = w * 64 + ct * 16 + l16;
        float bb = b_in[c];
        #pragma unroll
        for (int rt = 0; rt < 2; ++rt)
            #pragma unroll
            for (int i = 0; i < 4; ++i) {
                int row = rt * 16 + lg * 4 + i;
                sFF[row][c] = (bf16)gelu_f(a1[rt][ct][i] + bb);
            }
    }
    __syncthreads();

    // GEMM2: 32x512 @ 512x128
    f32x4 a2[2];
    a2[0] = (f32x4){0.f, 0.f, 0.f, 0.f}; a2[1] = (f32x4){0.f, 0.f, 0.f, 0.f};
    int cc = w * 16 + l16;
    #pragma unroll
    for (int kk = 0; kk < 16; ++kk) {
        bf16x8 af[2];
        #pragma unroll
        for (int rt = 0; rt < 2; ++rt)
            af[rt] = *(const bf16x8*)(&sFF[rt * 16 + l16][kk * 32 + lg * 8]);
        bf16x8 bfr = *(const bf16x8*)(&ws[245760 + (size_t)cc * 512 + kk * 32 + lg * 8]);
        #pragma unroll
        for (int rt = 0; rt < 2; ++rt)
            a2[rt] = __builtin_amdgcn_mfma_f32_16x16x32_bf16(af[rt], bfr, a2[rt], 0, 0, 0);
    }
    __syncthreads();   // all sFF reads done before sX overlay writes
    {
        float bb = b_out[cc];
        #pragma unroll
        for (int rt = 0; rt < 2; ++rt)
            #pragma unroll
            for (int i = 0; i < 4; ++i) {
                int row = rt * 16 + lg * 4 + i;
                sX[row][cc] = a2[rt][i] + bb + wsf[HVMID_F + (size_t)(n0 + row) * H + cc];
            }
    }
    __syncthreads();

    // LN2 + maskV; write outV f32, hV2 bf16, and stage hV2 tile for U2
    if (t < 128) {
        int row = t >> 2, q = t & 3;
        float xr[32], s1 = 0.f, s2 = 0.f;
        #pragma unroll
        for (int j = 0; j < 32; ++j) {
            float x = sX[row][q * 32 + j];
            xr[j] = x; s1 += x; s2 += x * x;
        }
        s1 += __shfl_xor(s1, 1); s1 += __shfl_xor(s1, 2);
        s2 += __shfl_xor(s2, 1); s2 += __shfl_xor(s2, 2);
        float m = s1 * (1.f / 128.f);
        float vv = s2 * (1.f / 128.f) - m * m;
        float rs = rsqrtf(vv + EPSF);
        float mv = maskV[n0 + row];
        #pragma unroll
        for (int j = 0; j < 32; ++j) {
            int c = q * 32 + j;
            float y = ((xr[j] - m) * rs * g2[c] + be2[c]) * mv;
            outV[(size_t)(n0 + row) * H + c] = y;
            ws[HV2_B + (size_t)(n0 + row) * H + c] = (bf16)y;
            sA[row][c] = (bf16)y;
        }
    }
    __syncthreads();

    // U2 = hV2 @ W11a + b11
    f32x4 a3[2];
    a3[0] = (f32x4){0.f, 0.f, 0.f, 0.f}; a3[1] = (f32x4){0.f, 0.f, 0.f, 0.f};
    #pragma unroll
    for (int kk = 0; kk < 4; ++kk) {
        bf16x8 af[2];
        #pragma unroll
        for (int rt = 0; rt < 2; ++rt)
            af[rt] = *(const bf16x8*)(&sA[rt * 16 + l16][kk * 32 + lg * 8]);
        bf16x8 bfr = *(const bf16x8*)(&ws[98304 + (size_t)cc * 384 + kk * 32 + lg * 8]);
        #pragma unroll
        for (int rt = 0; rt < 2; ++rt)
            a3[rt] = __builtin_amdgcn_mfma_f32_16x16x32_bf16(af[rt], bfr, a3[rt], 0, 0, 0);
    }
    {
        float bb = b11[cc];
        #pragma unroll
        for (int rt = 0; rt < 2; ++rt)
            #pragma unroll
            for (int i = 0; i < 4; ++i) {
                int row = rt * 16 + lg * 4 + i;
                wsf[U2_F + (size_t)(n0 + row) * H + cc] = a3[rt][i] + bb;
            }
    }
}

// ---------------- edge update: 2 nodes/block, segs {hE, hV2_nb} ----------------
__global__ __launch_bounds__(512, 4) void edge_kernel(
    const float* __restrict__ hE, const float* __restrict__ b12,
    const float* __restrict__ b13, const float* __restrict__ g3,
    const float* __restrict__ be3, const int* __restrict__ Eidx,
    const bf16* __restrict__ ws, const float* __restrict__ wsf,
    float* __restrict__ outE)
{
    int bn0 = blockIdx.x * 2;
    int b = bn0 >> 11;
    int t = threadIdx.x, w = t >> 6, l = t & 63, l16 = l & 15, lg = l >> 4;
    int wm = w >> 2, wn = w & 3;

    __shared__ __align__(16) char smem[52608];
    bf16 (*sA)[136]  = (bf16(*)[136])(smem);           // P: sA / sH2
    bf16 (*sH2)[136] = (bf16(*)[136])(smem);
    bf16 (*sH1)[136] = (bf16(*)[136])(smem + 26112);   // Q: sH1 / sM3
    bf16 (*sM3)[136] = (bf16(*)[136])(smem + 26112);
    int* sIdx = (int*)(smem + 52224);

    if (t < 96) sIdx[t] = Eidx[bn0 * 48 + t];

    f32x4 acc[3][2];
    #pragma unroll
    for (int rt = 0; rt < 3; ++rt)
        #pragma unroll
        for (int c2 = 0; c2 < 2; ++c2) acc[rt][c2] = (f32x4){0.f, 0.f, 0.f, 0.f};

    for (int seg = 0; seg < 2; ++seg) {
        if (seg == 0) __syncthreads();
        if (seg == 0) {
            #pragma unroll
            for (int i = 0; i < 6; ++i) {
                int idx = t + i * 512;
                int row = idx >> 5, c4 = (idx & 31) << 2;
                f32x4 v = *(const f32x4*)(hE + ((size_t)bn0 * 48 + row) * H + c4);
                bf16x4 o; o[0] = (bf16)v[0]; o[1] = (bf16)v[1]; o[2] = (bf16)v[2]; o[3] = (bf16)v[3];
                *(bf16x4*)(&sA[row][c4]) = o;
            }
        } else {
            const bf16* src = ws + HV2_B + (size_t)b * NN * H;
            #pragma unroll
            for (int i = 0; i < 3; ++i) {
                int idx = t + i * 512;
                int row = idx >> 4, c8 = (idx & 15) << 3;
                bf16x8 v = *(const bf16x8*)(src + (size_t)sIdx[row] * H + c8);
                *(bf16x8*)(&sA[row][c8]) = v;
            }
        }
        __syncthreads();
        #pragma unroll
        for (int kk = 0; kk < 4; ++kk) {
            bf16x8 af[3];
            #pragma unroll
            for (int rt = 0; rt < 3; ++rt)
                af[rt] = *(const bf16x8*)(&sA[wm * 48 + rt * 16 + l16][kk * 32 + lg * 8]);
            #pragma unroll
            for (int c2 = 0; c2 < 2; ++c2) {
                int c = wn * 32 + c2 * 16 + l16;
                bf16x8 bfr = *(const bf16x8*)(&ws[98304 + (size_t)c * 384 + 128 + seg * 128 + kk * 32 + lg * 8]);
                #pragma unroll
                for (int rt = 0; rt < 3; ++rt)
                    acc[rt][c2] = __builtin_amdgcn_mfma_f32_16x16x32_bf16(af[rt], bfr, acc[rt][c2], 0, 0, 0);
            }
        }
        __syncthreads();
    }
    #pragma unroll
    for (int c2 = 0; c2 < 2; ++c2) {
        int col = wn * 32 + c2 * 16 + l16;
        float u = wsf[U2_F + (size_t)(bn0 + wm) * H + col];
        #pragma unroll
        for (int rt = 0; rt < 3; ++rt)
            #pragma unroll
            for (int i = 0; i < 4; ++i) {
                int row = wm * 48 + rt * 16 + lg * 4 + i;
                sH1[row][col] = (bf16)gelu_f(acc[rt][c2][i] + u);
            }
    }
    __syncthreads();

    f32x4 a2[3][2];
    #pragma unroll
    for (int rt = 0; rt < 3; ++rt)
        #pragma unroll
        for (int c2 = 0; c2 < 2; ++c2) a2[rt][c2] = (f32x4){0.f, 0.f, 0.f, 0.f};
    #pragma unroll
    for (int kk = 0; kk < 4; ++kk) {
        bf16x8 af[3];
        #pragma unroll
        for (int rt = 0; rt < 3; ++rt)
            af[rt] = *(const bf16x8*)(&sH1[wm * 48 + rt * 16 + l16][kk * 32 + lg * 8]);
        #pragma unroll
        for (int c2 = 0; c2 < 2; ++c2) {
            int c = wn * 32 + c2 * 16 + l16;
            bf16x8 bfr = *(const bf16x8*)(&ws[147456 + (size_t)c * 128 + kk * 32 + lg * 8]);
            #pragma unroll
            for (int rt = 0; rt < 3; ++rt)
                a2[rt][c2] = __builtin_amdgcn_mfma_f32_16x16x32_bf16(af[rt], bfr, a2[rt][c2], 0, 0, 0);
        }
    }
    #pragma unroll
    for (int c2 = 0; c2 < 2; ++c2) {
        int col = wn * 32 + c2 * 16 + l16;
        float bb = b12[col];
        #pragma unroll
        for (int rt = 0; rt < 3; ++rt)
            #pragma unroll
            for (int i = 0; i < 4; ++i) {
                int row = wm * 48 + rt * 16 + lg * 4 + i;
                sH2[row][col] = (bf16)gelu_f(a2[rt][c2][i] + bb);
            }
    }
    __syncthreads();

    f32x4 a3[3][2];
    #pragma unroll
    for (int rt = 0; rt < 3; ++rt)
        #pragma unroll
        for (int c2 = 0; c2 < 2; ++c2) a3[rt][c2] = (f32x4){0.f, 0.f, 0.f, 0.f};
    #pragma unroll
    for (int kk = 0; kk < 4; ++kk) {
        bf16x8 af[3];
        #pragma unroll
        for (int rt = 0; rt < 3; ++rt)
            af[rt] = *(const bf16x8*)(&sH2[wm * 48 + rt * 16 + l16][kk * 32 + lg * 8]);
        #pragma unroll
        for (int c2 = 0; c2 < 2; ++c2) {
            int c = wn * 32 + c2 * 16 + l16;
            bf16x8 bfr = *(const bf16x8*)(&ws[163840 + (size_t)c * 128 + kk * 32 + lg * 8]);
            #pragma unroll
            for (int rt = 0; rt < 3; ++rt)
                a3[rt][c2] = __builtin_amdgcn_mfma_f32_16x16x32_bf16(af[rt], bfr, a3[rt][c2], 0, 0, 0);
        }
    }
    #pragma unroll
    for (int c2 = 0; c2 < 2; ++c2) {
        int col = wn * 32 + c2 * 16 + l16;
        float bb = b13[col];
        #pragma unroll
        for (int rt = 0; rt < 3; ++rt)
            #pragma unroll
            for (int i = 0; i < 4; ++i) {
                int row = wm * 48 + rt * 16 + lg * 4 + i;
                sM3[row][col] = (bf16)(a3[rt][c2][i] + bb);
            }
    }
    __syncthreads();

    // LN3(h_E + m3) per edge row, 4 threads/row
    if (t < 384) {
        int row = t >> 2, q = t & 3;
        size_t ebase = ((size_t)bn0 * 48 + row) * H + q * 32;
        float xr[32], s1 = 0.f, s2 = 0.f;
        #pragma unroll
        for (int jj = 0; jj < 8; ++jj) {
            f32x4 hv4 = *(const f32x4*)(hE + ebase + jj * 4);
            #pragma unroll
            for (int kq = 0; kq < 4; ++kq) {
                int j = jj * 4 + kq;
                float x = hv4[kq] + (float)sM3[row][q * 32 + j];
                xr[j] = x; s1 += x; s2 += x * x;
            }
        }
        s1 += __shfl_xor(s1, 1); s1 += __shfl_xor(s1, 2);
        s2 += __shfl_xor(s2, 1); s2 += __shfl_xor(s2, 2);
        float m = s1 * (1.f / 128.f);
        float vv = s2 * (1.f / 128.f) - m * m;
        float rs = rsqrtf(vv + EPSF);
        #pragma unroll
        for (int jj = 0; jj < 8; ++jj) {
            f32x4 o;
            #pragma unroll
            for (int kq = 0; kq < 4; ++kq) {
                int c = q * 32 + jj * 4 + kq;
                o[kq] = (xr[jj * 4 + kq] - m) * rs * g3[c] + be3[c];
            }
            *(f32x4*)(outE + ebase + jj * 4) = o;
        }
    }
}

extern "C" void kernel_launch(void* const* d_in, const int* in_sizes, int n_in,
                              void* d_out, int out_size, void* d_ws, size_t ws_size,
                              hipStream_t stream)
{
    const float* hV    = (const float*)d_in[0];
    const float* hVa   = (const float*)d_in[1];
    const float* hE    = (const float*)d_in[2];
    const float* W1    = (const float*)d_in[3];
    const float* b1    = (const float*)d_in[4];
    const float* W2    = (const float*)d_in[5];
    const float* b2    = (const float*)d_in[6];
    const float* W3    = (const float*)d_in[7];
    const float* b3    = (const float*)d_in[8];
    const float* W11   = (const float*)d_in[9];
    const float* b11   = (const float*)d_in[10];
    const float* W12   = (const float*)d_in[11];
    const float* b12   = (const float*)d_in[12];
    const float* W13   = (const float*)d_in[13];
    const float* b13   = (const float*)d_in[14];
    const float* Win   = (const float*)d_in[15];
    const float* b_in  = (const float*)d_in[16];
    const float* Wout  = (const float*)d_in[17];
    const float* b_out = (const float*)d_in[18];
    const float* g1    = (const float*)d_in[19];
    const float* be1   = (const float*)d_in[20];
    const float* g2    = (const float*)d_in[21];
    const float* be2   = (const float*)d_in[22];
    const float* g3    = (const float*)d_in[23];
    const float* be3   = (const float*)d_in[24];
    const float* maskV = (const float*)d_in[25];
    const float* maskA = (const float*)d_in[26];
    const int*   Eidx  = (const int*)  d_in[27];

    bf16*  ws   = (bf16*)d_ws;
    float* wsf  = (float*)d_ws;
    float* outV = (float*)d_out;
    float* outE = outV + (size_t)BB * NN * H;

    prep_weights<<<1216, 256, 0, stream>>>(W1, W2, W3, W11, W12, W13, Win, Wout, ws);
    u1_kernel<<<32, 512, 0, stream>>>(hV, hVa, b1, ws, wsf);
    node_msg_kernel<<<BB * NN / 2, 512, 0, stream>>>(hV, hE, b2, b3, g1, be1, maskA, Eidx, ws, wsf);
    ffn_kernel<<<BB * NN / 32, 512, 0, stream>>>(b_in, b_out, b11, g2, be2, maskV, ws, wsf, outV);
    edge_kernel<<<BB * NN / 2, 512, 0, stream>>>(hE, b12, b13, g3, be3, Eidx, ws, wsf, outE);
}

// Round 3
// 250.285 us; speedup vs baseline: 1.9220x; 1.1237x over previous
//
#include <hip/hip_runtime.h>
#include <hip/hip_bf16.h>

#define H 128
#define NN 2048
#define BB 2
#define EPSF 1e-5f

typedef __bf16 bf16;
typedef bf16 bf16x8 __attribute__((ext_vector_type(8)));
typedef bf16 bf16x4 __attribute__((ext_vector_type(4)));
typedef float f32x4 __attribute__((ext_vector_type(4)));

// ---- ws layout ----
// bf16 elems [0, 311296): weights
//   Wm1T full [128][512] @ 0      (k segs: self | hE-fold | hV_nb | hVa_nb)
//   W2T   @ 65536, W3T @ 81920
//   W11T full [128][384] @ 98304  (k segs: self | hE | hV2_nb)
//   W12T  @ 147456, W13T @ 163840
//   WinT [512][128] @ 180224, WoutT [128][512] @ 245760
// f32 elems (on (float*)ws):
#define U1_F     155648
#define U2_F     679936
#define HVMID_F  1204224
// bf16 elems:
#define HVMID_B  3457024
#define HV2_B    3981312
#define HV_B     4505600
#define HVA_B    5029888

// fast gelu: x * sigmoid(1.5957691*(x + 0.044715 x^3)) * 2-arg form
// exp(-2*0.7978845608*w) = exp2(-2.3022083*w)
__device__ __forceinline__ float gelu_f(float x) {
    float u = x * x;
    float p = __builtin_fmaf(u, 0.044715f, 1.0f);
    float w = x * p;
    float e = __builtin_amdgcn_exp2f(w * -2.3022083f);
    return x * __builtin_amdgcn_rcpf(1.0f + e);
}

// ---------------- weight prep ----------------
__global__ void prep_weights(const float* __restrict__ W1, const float* __restrict__ W2,
                             const float* __restrict__ W3, const float* __restrict__ W11,
                             const float* __restrict__ W12, const float* __restrict__ W13,
                             const float* __restrict__ Win, const float* __restrict__ Wout,
                             bf16* __restrict__ ws)
{
    int i = blockIdx.x * 256 + threadIdx.x;
    float v;
    if (i < 65536) {
        int c = i >> 9, k = i & 511, s = k >> 7, k0 = k & 127;
        if (s == 0)      v = W1[k0 * H + c];
        else if (s == 1) v = W1[(128 + k0) * H + c] + W1[(384 + k0) * H + c];
        else if (s == 2) v = W1[(256 + k0) * H + c];
        else             v = W1[(512 + k0) * H + c];
    } else if (i < 81920)  { int j = i - 65536;  int c = j >> 7, k = j & 127; v = W2[k * H + c]; }
    else if (i < 98304)    { int j = i - 81920;  int c = j >> 7, k = j & 127; v = W3[k * H + c]; }
    else if (i < 147456)   { int j = i - 98304;  int c = j / 384, k = j - c * 384; v = W11[k * H + c]; }
    else if (i < 163840)   { int j = i - 147456; int c = j >> 7, k = j & 127; v = W12[k * H + c]; }
    else if (i < 180224)   { int j = i - 163840; int c = j >> 7, k = j & 127; v = W13[k * H + c]; }
    else if (i < 245760)   { int j = i - 180224; int jj = j >> 7, k = j & 127; v = Win[k * 512 + jj]; }
    else                   { int j = i - 245760; int c = j >> 9, k = j & 511; v = Wout[k * H + c]; }
    ws[i] = (bf16)v;
}

// ---------------- U1 = hV @ W1a + b1 ; emit bf16 copies of hV, hVa ----------------
__global__ __launch_bounds__(512) void u1_kernel(
    const float* __restrict__ hV, const float* __restrict__ hVa,
    const float* __restrict__ b1, bf16* __restrict__ ws, float* __restrict__ wsf)
{
    int n0 = blockIdx.x * 128;
    int t = threadIdx.x, w = t >> 6, l = t & 63, l16 = l & 15, lg = l >> 4;
    int wm = w >> 2, wn = w & 3;
    __shared__ __align__(16) bf16 sA[128][136];

    #pragma unroll
    for (int i = 0; i < 8; ++i) {
        int idx = t + i * 512;
        int row = idx >> 5, c4 = (idx & 31) << 2;
        f32x4 v = *(const f32x4*)(hV + (size_t)(n0 + row) * H + c4);
        bf16x4 o; o[0] = (bf16)v[0]; o[1] = (bf16)v[1]; o[2] = (bf16)v[2]; o[3] = (bf16)v[3];
        *(bf16x4*)(&sA[row][c4]) = o;
        *(bf16x4*)(ws + HV_B + (size_t)(n0 + row) * H + c4) = o;
        f32x4 va = *(const f32x4*)(hVa + (size_t)(n0 + row) * H + c4);
        bf16x4 oa; oa[0] = (bf16)va[0]; oa[1] = (bf16)va[1]; oa[2] = (bf16)va[2]; oa[3] = (bf16)va[3];
        *(bf16x4*)(ws + HVA_B + (size_t)(n0 + row) * H + c4) = oa;
    }
    __syncthreads();

    f32x4 acc[4][2];
    #pragma unroll
    for (int rt = 0; rt < 4; ++rt)
        #pragma unroll
        for (int c2 = 0; c2 < 2; ++c2) acc[rt][c2] = (f32x4){0.f, 0.f, 0.f, 0.f};
    #pragma unroll
    for (int kk = 0; kk < 4; ++kk) {
        bf16x8 af[4];
        #pragma unroll
        for (int rt = 0; rt < 4; ++rt)
            af[rt] = *(const bf16x8*)(&sA[wm * 64 + rt * 16 + l16][kk * 32 + lg * 8]);
        #pragma unroll
        for (int c2 = 0; c2 < 2; ++c2) {
            int c = wn * 32 + c2 * 16 + l16;
            bf16x8 bfr = *(const bf16x8*)(&ws[(size_t)c * 512 + kk * 32 + lg * 8]);
            #pragma unroll
            for (int rt = 0; rt < 4; ++rt)
                acc[rt][c2] = __builtin_amdgcn_mfma_f32_16x16x32_bf16(af[rt], bfr, acc[rt][c2], 0, 0, 0);
        }
    }
    #pragma unroll
    for (int c2 = 0; c2 < 2; ++c2) {
        int col = wn * 32 + c2 * 16 + l16;
        float bb = b1[col];
        #pragma unroll
        for (int rt = 0; rt < 4; ++rt)
            #pragma unroll
            for (int i = 0; i < 4; ++i) {
                int row = wm * 64 + rt * 16 + lg * 4 + i;
                wsf[U1_F + (size_t)(n0 + row) * H + col] = acc[rt][c2][i] + bb;
            }
    }
}

// ---------------- node message: 2 nodes/block, M=96 ----------------
__global__ __launch_bounds__(512, 6) void node_msg_kernel(
    const float* __restrict__ hV, const float* __restrict__ hE,
    const float* __restrict__ b2, const float* __restrict__ b3,
    const float* __restrict__ g1, const float* __restrict__ be1,
    const float* __restrict__ maskA, const int* __restrict__ Eidx,
    bf16* __restrict__ ws, float* __restrict__ wsf)
{
    int bn0 = blockIdx.x * 2;
    int b = bn0 >> 11;
    int t = threadIdx.x, w = t >> 6, l = t & 63, l16 = l & 15, lg = l >> 4;
    int wm = w >> 2, wn = w & 3;

    __shared__ __align__(16) char smem[52992];
    bf16 (*sA)[136]  = (bf16(*)[136])(smem);           // P: sA / sH2
    bf16 (*sH2)[136] = (bf16(*)[136])(smem);
    bf16 (*sH1)[136] = (bf16(*)[136])(smem + 26112);   // Q
    float* sdh  = (float*)(smem + 26112);              // overlays Q (dead after GEMM2)
    float* sx   = (float*)(smem + 27136);
    float* sred = (float*)(smem + 28160);
    int*   sIdx = (int*)(smem + 52224);
    float* sMsk = (float*)(smem + 52608);

    if (t < 96) { sIdx[t] = Eidx[bn0 * 48 + t]; sMsk[t] = maskA[bn0 * 48 + t]; }
    __syncthreads();

    // hoisted scalar loads (hidden under staging)
    int col0 = wn * 32 + l16, col1 = col0 + 16;
    float u1v0 = wsf[U1_F + (size_t)(bn0 + wm) * H + col0];
    float u1v1 = wsf[U1_F + (size_t)(bn0 + wm) * H + col1];
    float b2v0 = b2[col0], b2v1 = b2[col1];
    float b3v0 = b3[col0], b3v1 = b3[col1];

    int r0 = t >> 4, c8g = (t & 15) << 3;
    bf16x8 gth[3];
    {   // prefetch gather 1 (hV neighbors)
        const bf16* src = ws + HV_B + (size_t)b * NN * H;
        #pragma unroll
        for (int i = 0; i < 3; ++i)
            gth[i] = *(const bf16x8*)(src + (size_t)sIdx[r0 + i * 32] * H + c8g);
    }
    // stage hE (f32 -> bf16)
    #pragma unroll
    for (int i = 0; i < 6; ++i) {
        int idx = t + i * 512;
        int row = idx >> 5, c4 = (idx & 31) << 2;
        f32x4 v = *(const f32x4*)(hE + ((size_t)bn0 * 48 + row) * H + c4);
        bf16x4 o; o[0] = (bf16)v[0]; o[1] = (bf16)v[1]; o[2] = (bf16)v[2]; o[3] = (bf16)v[3];
        *(bf16x4*)(&sA[row][c4]) = o;
    }
    __syncthreads();

    f32x4 acc[3][2];
    #pragma unroll
    for (int rt = 0; rt < 3; ++rt)
        #pragma unroll
        for (int c2 = 0; c2 < 2; ++c2) acc[rt][c2] = (f32x4){0.f, 0.f, 0.f, 0.f};

    auto gemm1 = [&](int woff) {
        #pragma unroll
        for (int kk = 0; kk < 4; ++kk) {
            bf16x8 af[3];
            #pragma unroll
            for (int rt = 0; rt < 3; ++rt)
                af[rt] = *(const bf16x8*)(&sA[wm * 48 + rt * 16 + l16][kk * 32 + lg * 8]);
            #pragma unroll
            for (int c2 = 0; c2 < 2; ++c2) {
                int c = wn * 32 + c2 * 16 + l16;
                bf16x8 bfr = *(const bf16x8*)(&ws[(size_t)c * 512 + woff + kk * 32 + lg * 8]);
                #pragma unroll
                for (int rt = 0; rt < 3; ++rt)
                    acc[rt][c2] = __builtin_amdgcn_mfma_f32_16x16x32_bf16(af[rt], bfr, acc[rt][c2], 0, 0, 0);
            }
        }
    };

    gemm1(128);                       // hE segment
    __syncthreads();
    #pragma unroll
    for (int i = 0; i < 3; ++i) *(bf16x8*)(&sA[r0 + i * 32][c8g]) = gth[i];
    {   // prefetch gather 2 (hVa neighbors)
        const bf16* src = ws + HVA_B + (size_t)b * NN * H;
        #pragma unroll
        for (int i = 0; i < 3; ++i)
            gth[i] = *(const bf16x8*)(src + (size_t)sIdx[r0 + i * 32] * H + c8g);
    }
    __syncthreads();
    gemm1(256);                       // hV_nb segment
    __syncthreads();
    #pragma unroll
    for (int i = 0; i < 3; ++i) *(bf16x8*)(&sA[r0 + i * 32][c8g]) = gth[i];
    __syncthreads();
    gemm1(384);                       // hVa_nb segment

    // epi1: + U1 (contains b1), gelu -> sH1 (Q). No barrier needed: Q untouched,
    // epi writes don't conflict with other waves' P reads.
    #pragma unroll
    for (int c2 = 0; c2 < 2; ++c2) {
        int col = c2 ? col1 : col0;
        float u = c2 ? u1v1 : u1v0;
        #pragma unroll
        for (int rt = 0; rt < 3; ++rt)
            #pragma unroll
            for (int i = 0; i < 4; ++i) {
                int row = wm * 48 + rt * 16 + lg * 4 + i;
                sH1[row][col] = (bf16)gelu_f(acc[rt][c2][i] + u);
            }
    }
    __syncthreads();

    // GEMM2 (reads Q)
    f32x4 a2[3][2];
    #pragma unroll
    for (int rt = 0; rt < 3; ++rt)
        #pragma unroll
        for (int c2 = 0; c2 < 2; ++c2) a2[rt][c2] = (f32x4){0.f, 0.f, 0.f, 0.f};
    #pragma unroll
    for (int kk = 0; kk < 4; ++kk) {
        bf16x8 af[3];
        #pragma unroll
        for (int rt = 0; rt < 3; ++rt)
            af[rt] = *(const bf16x8*)(&sH1[wm * 48 + rt * 16 + l16][kk * 32 + lg * 8]);
        #pragma unroll
        for (int c2 = 0; c2 < 2; ++c2) {
            int c = wn * 32 + c2 * 16 + l16;
            bf16x8 bfr = *(const bf16x8*)(&ws[65536 + (size_t)c * 128 + kk * 32 + lg * 8]);
            #pragma unroll
            for (int rt = 0; rt < 3; ++rt)
                a2[rt][c2] = __builtin_amdgcn_mfma_f32_16x16x32_bf16(af[rt], bfr, a2[rt][c2], 0, 0, 0);
        }
    }
    // epi2 -> sH2 (P). Barrier after epi1 guarantees all P reads (gemm1) done.
    #pragma unroll
    for (int c2 = 0; c2 < 2; ++c2) {
        int col = c2 ? col1 : col0;
        float bb = c2 ? b2v1 : b2v0;
        #pragma unroll
        for (int rt = 0; rt < 3; ++rt)
            #pragma unroll
            for (int i = 0; i < 4; ++i) {
                int row = wm * 48 + rt * 16 + lg * 4 + i;
                sH2[row][col] = (bf16)gelu_f(a2[rt][c2][i] + bb);
            }
    }
    __syncthreads();

    // GEMM3 (reads P) + masked reduce over 48 edges
    f32x4 a3[3][2];
    #pragma unroll
    for (int rt = 0; rt < 3; ++rt)
        #pragma unroll
        for (int c2 = 0; c2 < 2; ++c2) a3[rt][c2] = (f32x4){0.f, 0.f, 0.f, 0.f};
    #pragma unroll
    for (int kk = 0; kk < 4; ++kk) {
        bf16x8 af[3];
        #pragma unroll
        for (int rt = 0; rt < 3; ++rt)
            af[rt] = *(const bf16x8*)(&sH2[wm * 48 + rt * 16 + l16][kk * 32 + lg * 8]);
        #pragma unroll
        for (int c2 = 0; c2 < 2; ++c2) {
            int c = wn * 32 + c2 * 16 + l16;
            bf16x8 bfr = *(const bf16x8*)(&ws[81920 + (size_t)c * 128 + kk * 32 + lg * 8]);
            #pragma unroll
            for (int rt = 0; rt < 3; ++rt)
                a3[rt][c2] = __builtin_amdgcn_mfma_f32_16x16x32_bf16(af[rt], bfr, a3[rt][c2], 0, 0, 0);
        }
    }
    #pragma unroll
    for (int c2 = 0; c2 < 2; ++c2) {
        float bb = c2 ? b3v1 : b3v0;
        float s = 0.f;
        #pragma unroll
        for (int rt = 0; rt < 3; ++rt)
            #pragma unroll
            for (int i = 0; i < 4; ++i) {
                int ri = rt * 16 + lg * 4 + i;
                s += (a3[rt][c2][i] + bb) * sMsk[wm * 48 + ri];
            }
        s += __shfl_xor(s, 16);
        s += __shfl_xor(s, 32);
        // sdh overlays Q: barrier after epi2 guarantees all Q reads (GEMM2) done.
        if (l < 16) sdh[wm * 128 + wn * 32 + c2 * 16 + l16] = s;
    }
    __syncthreads();

    // LN1 over 2 nodes
    if (t < 256) {
        int nl = t >> 7, col = t & 127;
        sx[t] = hV[(size_t)(bn0 + nl) * H + col] + sdh[t] * (1.0f / 30.0f);
    }
    __syncthreads();
    if (w < 2) {
        float xa = sx[w * 128 + l], xb = sx[w * 128 + l + 64];
        float s1 = xa + xb, s2 = xa * xa + xb * xb;
        #pragma unroll
        for (int off = 32; off; off >>= 1) { s1 += __shfl_xor(s1, off); s2 += __shfl_xor(s2, off); }
        if (l == 0) { float m = s1 * (1.f / 128.f); sred[w * 2] = m; sred[w * 2 + 1] = s2 * (1.f / 128.f) - m * m; }
    }
    __syncthreads();
    if (t < 256) {
        int nl = t >> 7, col = t & 127;
        float y = (sx[t] - sred[nl * 2]) * rsqrtf(sred[nl * 2 + 1] + EPSF) * g1[col] + be1[col];
        wsf[HVMID_F + (size_t)(bn0 + nl) * H + col] = y;
        ws[HVMID_B + (size_t)(bn0 + nl) * H + col] = (bf16)y;
    }
}

// ---------------- FFN batched: 32 nodes/block, + LN2 + maskV + U2 ----------------
__global__ __launch_bounds__(512) void ffn_kernel(
    const float* __restrict__ b_in, const float* __restrict__ b_out,
    const float* __restrict__ b11, const float* __restrict__ g2,
    const float* __restrict__ be2, const float* __restrict__ maskV,
    bf16* __restrict__ ws, float* __restrict__ wsf, float* __restrict__ outV)
{
    int n0 = blockIdx.x * 32;
    int t = threadIdx.x, w = t >> 6, l = t & 63, l16 = l & 15, lg = l >> 4;

    __shared__ __align__(16) char smem[8704 + 33280];
    bf16 (*sA)[136]  = (bf16(*)[136])(smem);
    bf16 (*sFF)[520] = (bf16(*)[520])(smem + 8704);
    float (*sX)[132] = (float(*)[132])(smem + 8704);   // overlays sFF

    {
        int row = t >> 4, c8 = (t & 15) << 3;
        *(bf16x8*)(&sA[row][c8]) = *(const bf16x8*)(ws + HVMID_B + (size_t)(n0 + row) * H + c8);
    }
    __syncthreads();

    // GEMM1: 32x128 @ 128x512
    f32x4 a1[2][4];
    #pragma unroll
    for (int rt = 0; rt < 2; ++rt)
        #pragma unroll
        for (int ct = 0; ct < 4; ++ct) a1[rt][ct] = (f32x4){0.f, 0.f, 0.f, 0.f};
    #pragma unroll
    for (int kk = 0; kk < 4; ++kk) {
        bf16x8 af[2];
        #pragma unroll
        for (int rt = 0; rt < 2; ++rt)
            af[rt] = *(const bf16x8*)(&sA[rt * 16 + l16][kk * 32 + lg * 8]);
        #pragma unroll
        for (int ct = 0; ct < 4; ++ct) {
            int c = w * 64 + ct * 16 + l16;
            bf16x8 bfr = *(const bf16x8*)(&ws[180224 + (size_t)c * 128 + kk * 32 + lg * 8]);
            #pragma unroll
            for (int rt = 0; rt < 2; ++rt)
                a1[rt][ct] = __builtin_amdgcn_mfma_f32_16x16x32_bf16(af[rt], bfr, a1[rt][ct], 0, 0, 0);
        }
    }
    #pragma unroll
    for (int ct = 0; ct < 4; ++ct) {
        int c = w * 64 + ct * 16 + l16;
        float bb = b_in[c];
        #pragma unroll
        for (int rt = 0; rt < 2; ++rt)
            #pragma unroll
            for (int i = 0; i < 4; ++i) {
                int row = rt * 16 + lg * 4 + i;
                sFF[row][c] = (bf16)gelu_f(a1[rt][ct][i] + bb);
            }
    }
    __syncthreads();

    // GEMM2: 32x512 @ 512x128
    f32x4 a2[2];
    a2[0] = (f32x4){0.f, 0.f, 0.f, 0.f}; a2[1] = (f32x4){0.f, 0.f, 0.f, 0.f};
    int cc = w * 16 + l16;
    #pragma unroll
    for (int kk = 0; kk < 16; ++kk) {
        bf16x8 af[2];
        #pragma unroll
        for (int rt = 0; rt < 2; ++rt)
            af[rt] = *(const bf16x8*)(&sFF[rt * 16 + l16][kk * 32 + lg * 8]);
        bf16x8 bfr = *(const bf16x8*)(&ws[245760 + (size_t)cc * 512 + kk * 32 + lg * 8]);
        #pragma unroll
        for (int rt = 0; rt < 2; ++rt)
            a2[rt] = __builtin_amdgcn_mfma_f32_16x16x32_bf16(af[rt], bfr, a2[rt], 0, 0, 0);
    }
    __syncthreads();   // all sFF reads done before sX overlay writes
    {
        float bb = b_out[cc];
        #pragma unroll
        for (int rt = 0; rt < 2; ++rt)
            #pragma unroll
            for (int i = 0; i < 4; ++i) {
                int row = rt * 16 + lg * 4 + i;
                sX[row][cc] = a2[rt][i] + bb + wsf[HVMID_F + (size_t)(n0 + row) * H + cc];
            }
    }
    __syncthreads();

    // LN2 + maskV; write outV f32, hV2 bf16, stage hV2 tile for U2
    if (t < 128) {
        int row = t >> 2, q = t & 3;
        float xr[32], s1 = 0.f, s2 = 0.f;
        #pragma unroll
        for (int j = 0; j < 32; ++j) {
            float x = sX[row][q * 32 + j];
            xr[j] = x; s1 += x; s2 += x * x;
        }
        s1 += __shfl_xor(s1, 1); s1 += __shfl_xor(s1, 2);
        s2 += __shfl_xor(s2, 1); s2 += __shfl_xor(s2, 2);
        float m = s1 * (1.f / 128.f);
        float vv = s2 * (1.f / 128.f) - m * m;
        float rs = rsqrtf(vv + EPSF);
        float mv = maskV[n0 + row];
        #pragma unroll
        for (int j = 0; j < 32; ++j) {
            int c = q * 32 + j;
            float y = ((xr[j] - m) * rs * g2[c] + be2[c]) * mv;
            outV[(size_t)(n0 + row) * H + c] = y;
            ws[HV2_B + (size_t)(n0 + row) * H + c] = (bf16)y;
            sA[row][c] = (bf16)y;
        }
    }
    __syncthreads();

    // U2 = hV2 @ W11a + b11
    f32x4 a3[2];
    a3[0] = (f32x4){0.f, 0.f, 0.f, 0.f}; a3[1] = (f32x4){0.f, 0.f, 0.f, 0.f};
    #pragma unroll
    for (int kk = 0; kk < 4; ++kk) {
        bf16x8 af[2];
        #pragma unroll
        for (int rt = 0; rt < 2; ++rt)
            af[rt] = *(const bf16x8*)(&sA[rt * 16 + l16][kk * 32 + lg * 8]);
        bf16x8 bfr = *(const bf16x8*)(&ws[98304 + (size_t)cc * 384 + kk * 32 + lg * 8]);
        #pragma unroll
        for (int rt = 0; rt < 2; ++rt)
            a3[rt] = __builtin_amdgcn_mfma_f32_16x16x32_bf16(af[rt], bfr, a3[rt], 0, 0, 0);
    }
    {
        float bb = b11[cc];
        #pragma unroll
        for (int rt = 0; rt < 2; ++rt)
            #pragma unroll
            for (int i = 0; i < 4; ++i) {
                int row = rt * 16 + lg * 4 + i;
                wsf[U2_F + (size_t)(n0 + row) * H + cc] = a3[rt][i] + bb;
            }
    }
}

// ---------------- edge update: 2 nodes/block ----------------
__global__ __launch_bounds__(512, 6) void edge_kernel(
    const float* __restrict__ hE, const float* __restrict__ b12,
    const float* __restrict__ b13, const float* __restrict__ g3,
    const float* __restrict__ be3, const int* __restrict__ Eidx,
    const bf16* __restrict__ ws, const float* __restrict__ wsf,
    float* __restrict__ outE)
{
    int bn0 = blockIdx.x * 2;
    int b = bn0 >> 11;
    int t = threadIdx.x, w = t >> 6, l = t & 63, l16 = l & 15, lg = l >> 4;
    int wm = w >> 2, wn = w & 3;

    __shared__ __align__(16) char smem[52608];
    bf16 (*sA)[136]  = (bf16(*)[136])(smem);           // P: sA / sH2
    bf16 (*sH2)[136] = (bf16(*)[136])(smem);
    bf16 (*sH1)[136] = (bf16(*)[136])(smem + 26112);   // Q: sH1 / sM3
    bf16 (*sM3)[136] = (bf16(*)[136])(smem + 26112);
    int* sIdx = (int*)(smem + 52224);

    if (t < 96) sIdx[t] = Eidx[bn0 * 48 + t];
    __syncthreads();

    int col0 = wn * 32 + l16, col1 = col0 + 16;
    float u2v0 = wsf[U2_F + (size_t)(bn0 + wm) * H + col0];
    float u2v1 = wsf[U2_F + (size_t)(bn0 + wm) * H + col1];
    float b12v0 = b12[col0], b12v1 = b12[col1];
    float b13v0 = b13[col0], b13v1 = b13[col1];

    int r0 = t >> 4, c8g = (t & 15) << 3;
    bf16x8 gth[3];
    {   // prefetch gather (hV2 neighbors)
        const bf16* src = ws + HV2_B + (size_t)b * NN * H;
        #pragma unroll
        for (int i = 0; i < 3; ++i)
            gth[i] = *(const bf16x8*)(src + (size_t)sIdx[r0 + i * 32] * H + c8g);
    }
    // stage hE
    #pragma unroll
    for (int i = 0; i < 6; ++i) {
        int idx = t + i * 512;
        int row = idx >> 5, c4 = (idx & 31) << 2;
        f32x4 v = *(const f32x4*)(hE + ((size_t)bn0 * 48 + row) * H + c4);
        bf16x4 o; o[0] = (bf16)v[0]; o[1] = (bf16)v[1]; o[2] = (bf16)v[2]; o[3] = (bf16)v[3];
        *(bf16x4*)(&sA[row][c4]) = o;
    }
    __syncthreads();

    f32x4 acc[3][2];
    #pragma unroll
    for (int rt = 0; rt < 3; ++rt)
        #pragma unroll
        for (int c2 = 0; c2 < 2; ++c2) acc[rt][c2] = (f32x4){0.f, 0.f, 0.f, 0.f};

    auto gemm1 = [&](int woff) {
        #pragma unroll
        for (int kk = 0; kk < 4; ++kk) {
            bf16x8 af[3];
            #pragma unroll
            for (int rt = 0; rt < 3; ++rt)
                af[rt] = *(const bf16x8*)(&sA[wm * 48 + rt * 16 + l16][kk * 32 + lg * 8]);
            #pragma unroll
            for (int c2 = 0; c2 < 2; ++c2) {
                int c = wn * 32 + c2 * 16 + l16;
                bf16x8 bfr = *(const bf16x8*)(&ws[98304 + (size_t)c * 384 + woff + kk * 32 + lg * 8]);
                #pragma unroll
                for (int rt = 0; rt < 3; ++rt)
                    acc[rt][c2] = __builtin_amdgcn_mfma_f32_16x16x32_bf16(af[rt], bfr, acc[rt][c2], 0, 0, 0);
            }
        }
    };

    gemm1(128);                       // hE segment
    __syncthreads();
    #pragma unroll
    for (int i = 0; i < 3; ++i) *(bf16x8*)(&sA[r0 + i * 32][c8g]) = gth[i];
    __syncthreads();
    gemm1(256);                       // hV2_nb segment

    // epi1 -> sH1 (Q), no barrier needed before
    #pragma unroll
    for (int c2 = 0; c2 < 2; ++c2) {
        int col = c2 ? col1 : col0;
        float u = c2 ? u2v1 : u2v0;
        #pragma unroll
        for (int rt = 0; rt < 3; ++rt)
            #pragma unroll
            for (int i = 0; i < 4; ++i) {
                int row = wm * 48 + rt * 16 + lg * 4 + i;
                sH1[row][col] = (bf16)gelu_f(acc[rt][c2][i] + u);
            }
    }
    __syncthreads();

    // GEMM2 (reads Q)
    f32x4 a2[3][2];
    #pragma unroll
    for (int rt = 0; rt < 3; ++rt)
        #pragma unroll
        for (int c2 = 0; c2 < 2; ++c2) a2[rt][c2] = (f32x4){0.f, 0.f, 0.f, 0.f};
    #pragma unroll
    for (int kk = 0; kk < 4; ++kk) {
        bf16x8 af[3];
        #pragma unroll
        for (int rt = 0; rt < 3; ++rt)
            af[rt] = *(const bf16x8*)(&sH1[wm * 48 + rt * 16 + l16][kk * 32 + lg * 8]);
        #pragma unroll
        for (int c2 = 0; c2 < 2; ++c2) {
            int c = wn * 32 + c2 * 16 + l16;
            bf16x8 bfr = *(const bf16x8*)(&ws[147456 + (size_t)c * 128 + kk * 32 + lg * 8]);
            #pragma unroll
            for (int rt = 0; rt < 3; ++rt)
                a2[rt][c2] = __builtin_amdgcn_mfma_f32_16x16x32_bf16(af[rt], bfr, a2[rt][c2], 0, 0, 0);
        }
    }
    // epi2 -> sH2 (P); barrier after epi1 covered P's reads
    #pragma unroll
    for (int c2 = 0; c2 < 2; ++c2) {
        int col = c2 ? col1 : col0;
        float bb = c2 ? b12v1 : b12v0;
        #pragma unroll
        for (int rt = 0; rt < 3; ++rt)
            #pragma unroll
            for (int i = 0; i < 4; ++i) {
                int row = wm * 48 + rt * 16 + lg * 4 + i;
                sH2[row][col] = (bf16)gelu_f(a2[rt][c2][i] + bb);
            }
    }
    __syncthreads();

    // GEMM3 (reads P)
    f32x4 a3[3][2];
    #pragma unroll
    for (int rt = 0; rt < 3; ++rt)
        #pragma unroll
        for (int c2 = 0; c2 < 2; ++c2) a3[rt][c2] = (f32x4){0.f, 0.f, 0.f, 0.f};
    #pragma unroll
    for (int kk = 0; kk < 4; ++kk) {
        bf16x8 af[3];
        #pragma unroll
        for (int rt = 0; rt < 3; ++rt)
            af[rt] = *(const bf16x8*)(&sH2[wm * 48 + rt * 16 + l16][kk * 32 + lg * 8]);
        #pragma unroll
        for (int c2 = 0; c2 < 2; ++c2) {
            int c = wn * 32 + c2 * 16 + l16;
            bf16x8 bfr = *(const bf16x8*)(&ws[163840 + (size_t)c * 128 + kk * 32 + lg * 8]);
            #pragma unroll
            for (int rt = 0; rt < 3; ++rt)
                a3[rt][c2] = __builtin_amdgcn_mfma_f32_16x16x32_bf16(af[rt], bfr, a3[rt][c2], 0, 0, 0);
        }
    }
    // epi3 -> sM3 (Q); barrier after epi2 covered Q's reads
    #pragma unroll
    for (int c2 = 0; c2 < 2; ++c2) {
        int col = c2 ? col1 : col0;
        float bb = c2 ? b13v1 : b13v0;
        #pragma unroll
        for (int rt = 0; rt < 3; ++rt)
            #pragma unroll
            for (int i = 0; i < 4; ++i) {
                int row = wm * 48 + rt * 16 + lg * 4 + i;
                sM3[row][col] = (bf16)(a3[rt][c2][i] + bb);
            }
    }
    __syncthreads();

    // LN3(h_E + m3) per edge row, 4 threads/row
    if (t < 384) {
        int row = t >> 2, q = t & 3;
        size_t ebase = ((size_t)bn0 * 48 + row) * H + q * 32;
        float xr[32], s1 = 0.f, s2 = 0.f;
        #pragma unroll
        for (int jj = 0; jj < 8; ++jj) {
            f32x4 hv4 = *(const f32x4*)(hE + ebase + jj * 4);
            #pragma unroll
            for (int kq = 0; kq < 4; ++kq) {
                int j = jj * 4 + kq;
                float x = hv4[kq] + (float)sM3[row][q * 32 + j];
                xr[j] = x; s1 += x; s2 += x * x;
            }
        }
        s1 += __shfl_xor(s1, 1); s1 += __shfl_xor(s1, 2);
        s2 += __shfl_xor(s2, 1); s2 += __shfl_xor(s2, 2);
        float m = s1 * (1.f / 128.f);
        float vv = s2 * (1.f / 128.f) - m * m;
        float rs = rsqrtf(vv + EPSF);
        #pragma unroll
        for (int jj = 0; jj < 8; ++jj) {
            f32x4 o;
            #pragma unroll
            for (int kq = 0; kq < 4; ++kq) {
                int c = q * 32 + jj * 4 + kq;
                o[kq] = (xr[jj * 4 + kq] - m) * rs * g3[c] + be3[c];
            }
            *(f32x4*)(outE + ebase + jj * 4) = o;
        }
    }
}

extern "C" void kernel_launch(void* const* d_in, const int* in_sizes, int n_in,
                              void* d_out, int out_size, void* d_ws, size_t ws_size,
                              hipStream_t stream)
{
    const float* hV    = (const float*)d_in[0];
    const float* hVa   = (const float*)d_in[1];
    const float* hE    = (const float*)d_in[2];
    const float* W1    = (const float*)d_in[3];
    const float* b1    = (const float*)d_in[4];
    const float* W2    = (const float*)d_in[5];
    const float* b2    = (const float*)d_in[6];
    const float* W3    = (const float*)d_in[7];
    const float* b3    = (const float*)d_in[8];
    const float* W11   = (const float*)d_in[9];
    const float* b11   = (const float*)d_in[10];
    const float* W12   = (const float*)d_in[11];
    const float* b12   = (const float*)d_in[12];
    const float* W13   = (const float*)d_in[13];
    const float* b13   = (const float*)d_in[14];
    const float* Win   = (const float*)d_in[15];
    const float* b_in  = (const float*)d_in[16];
    const float* Wout  = (const float*)d_in[17];
    const float* b_out = (const float*)d_in[18];
    const float* g1    = (const float*)d_in[19];
    const float* be1   = (const float*)d_in[20];
    const float* g2    = (const float*)d_in[21];
    const float* be2   = (const float*)d_in[22];
    const float* g3    = (const float*)d_in[23];
    const float* be3   = (const float*)d_in[24];
    const float* maskV = (const float*)d_in[25];
    const float* maskA = (const float*)d_in[26];
    const int*   Eidx  = (const int*)  d_in[27];

    bf16*  ws   = (bf16*)d_ws;
    float* wsf  = (float*)d_ws;
    float* outV = (float*)d_out;
    float* outE = outV + (size_t)BB * NN * H;

    prep_weights<<<1216, 256, 0, stream>>>(W1, W2, W3, W11, W12, W13, Win, Wout, ws);
    u1_kernel<<<32, 512, 0, stream>>>(hV, hVa, b1, ws, wsf);
    node_msg_kernel<<<BB * NN / 2, 512, 0, stream>>>(hV, hE, b2, b3, g1, be1, maskA, Eidx, ws, wsf);
    ffn_kernel<<<BB * NN / 32, 512, 0, stream>>>(b_in, b_out, b11, g2, be2, maskV, ws, wsf, outV);
    edge_kernel<<<BB * NN / 2, 512, 0, stream>>>(hE, b12, b13, g3, be3, Eidx, ws, wsf, outE);
}